// Round 20
// baseline (284.027 us; speedup 1.0000x reference)
//
#include <hip/hip_runtime.h>
#include <hip/hip_bf16.h>
#include <cstdint>
#include <cstddef>

#define Bdim 2
#define Sdim 2048
#define Edim 1024
#define Hdim 16
#define Ddim 64
#define KVB 128
#define MROWS (Bdim*Sdim)
#define QSCALE (0.125f * 1.44269504088896f)   // 1/sqrt(D) * log2(e): exp(s)=exp2(s')

typedef __bf16 bf16_t;
typedef __attribute__((ext_vector_type(8))) __bf16 bf16x8;
typedef __attribute__((ext_vector_type(4))) __bf16 bf16x4;
typedef __attribute__((ext_vector_type(4))) float f32x4;

typedef __attribute__((address_space(3))) uint8_t lds8_t;
typedef const __attribute__((address_space(1))) uint8_t glb8_t;

__device__ inline bf16_t f2b(float x) {
    unsigned u = __builtin_bit_cast(unsigned, x);
    unsigned r = u + 0x7fffu + ((u >> 16) & 1u);
    return __builtin_bit_cast(bf16_t, (unsigned short)(r >> 16));
}

// m97-class bf16 GEMM core: C[128x128] = A[128xK] * B^T (B row-major [128-col
// band][K]). 4 waves 2x2, 16x16x32 MFMA, 4x4 frags/wave. Staging via
// global_load_lds width=16 into LINEAR LDS [128][32] bf16.
__device__ inline void gemm_async(const bf16_t* A, const bf16_t* B, int K,
                                  f32x4 (&acc)[4][4]) {
    __shared__ __align__(16) bf16_t As[128 * 32];
    __shared__ __align__(16) bf16_t Bs[128 * 32];
    const int tid = threadIdx.x;
    const int lane = tid & 63;
    const int w = tid >> 6;
    const int wm = w >> 1, wn = w & 1;
    const int lr = lane & 15, lg = lane >> 4;

    #pragma unroll
    for (int mi = 0; mi < 4; ++mi)
        #pragma unroll
        for (int ni = 0; ni < 4; ++ni)
            acc[mi][ni] = (f32x4){0.f, 0.f, 0.f, 0.f};

    const int srow = (lane >> 2);
    const int scol = (lane & 3) * 8;

    for (int kt = 0; kt < K; kt += 32) {
        __syncthreads();
        #pragma unroll
        for (int i = 0; i < 2; ++i) {
            const int chunk = w * 2 + i;
            const int row = chunk * 16 + srow;
            __builtin_amdgcn_global_load_lds(
                (glb8_t*)(A + (size_t)row * K + kt + scol),
                (lds8_t*)(As + chunk * 512), 16, 0, 0);
            __builtin_amdgcn_global_load_lds(
                (glb8_t*)(B + (size_t)row * K + kt + scol),
                (lds8_t*)(Bs + chunk * 512), 16, 0, 0);
        }
        __syncthreads();
        bf16x8 af[4], bf[4];
        #pragma unroll
        for (int mi = 0; mi < 4; ++mi)
            af[mi] = *(const bf16x8*)&As[(wm * 64 + mi * 16 + lr) * 32 + lg * 8];
        #pragma unroll
        for (int ni = 0; ni < 4; ++ni)
            bf[ni] = *(const bf16x8*)&Bs[(wn * 64 + ni * 16 + lr) * 32 + lg * 8];
        #pragma unroll
        for (int mi = 0; mi < 4; ++mi)
            #pragma unroll
            for (int ni = 0; ni < 4; ++ni)
                acc[mi][ni] = __builtin_amdgcn_mfma_f32_16x16x32_bf16(
                    af[mi], bf[ni], acc[mi][ni], 0, 0, 0);
    }
}

// ---- Kernel 0: convert weights AND the 3 input activations to bf16.
__global__ __launch_bounds__(256) void k_convert(
    const float* __restrict__ Wq, const float* __restrict__ Wk,
    const float* __restrict__ Wv, const float* __restrict__ Wo,
    const float* __restrict__ xq, const float* __restrict__ xk,
    const float* __restrict__ xv,
    bf16_t* __restrict__ Wb, bf16_t* __restrict__ Xb) {
    const int z = blockIdx.y;
    const float* src;
    bf16_t* d;
    float scale = 1.0f;
    if (z < 4) {
        if (blockIdx.x >= 512) return;
        src = (z == 0) ? Wq : (z == 1) ? Wk : (z == 2) ? Wv : Wo;
        scale = (z == 0) ? QSCALE : 1.0f;
        d = Wb + (size_t)z * Edim * Edim;
    } else {
        src = (z == 4) ? xq : (z == 5) ? xk : xv;
        d = Xb + (size_t)(z - 4) * MROWS * Edim;
    }
    const size_t i = (size_t)blockIdx.x * 256 + threadIdx.x;
    const float4* s4 = (const float4*)(src + i * 8);
    float4 a = s4[0], b = s4[1];
    bf16x8 v;
    v[0] = f2b(a.x * scale); v[1] = f2b(a.y * scale);
    v[2] = f2b(a.z * scale); v[3] = f2b(a.w * scale);
    v[4] = f2b(b.x * scale); v[5] = f2b(b.y * scale);
    v[6] = f2b(b.z * scale); v[7] = f2b(b.w * scale);
    *(bf16x8*)(d + i * 8) = v;
}

// ---- Kernel 1: QKV projections, m97-class bf16 GEMM.
// Q (pre-scaled by QSCALE = 0.125*log2e) -> [B,H,S,D]; K,V fragment-major:
//   Kswz[bh][s/16][d/8][s%16][d%8]
//   Vswz[bh][s/32][d/16][(s/8)%4][d%16][s%8]
__global__ __launch_bounds__(256) void k_proj(
    const bf16_t* __restrict__ Xb, const bf16_t* __restrict__ Wb,
    const float* __restrict__ bq, const float* __restrict__ bk, const float* __restrict__ bv,
    bf16_t* __restrict__ Qb, bf16_t* __restrict__ Kswz, bf16_t* __restrict__ Vswz) {
    const int z = blockIdx.z;
    const bf16_t* X = Xb + (size_t)z * MROWS * Edim;
    const bf16_t* W = Wb + (size_t)z * Edim * Edim;
    const float* bias = (z == 0) ? bq : (z == 1) ? bk : bv;
    const float bscale = (z == 0) ? QSCALE : 1.0f;
    const int tm = blockIdx.y, tn = blockIdx.x;
    f32x4 acc[4][4];
    gemm_async(X + (size_t)tm * 128 * Edim, W + (size_t)tn * 128 * Edim, Edim, acc);
    const int tid = threadIdx.x, lane = tid & 63, w = tid >> 6;
    const int wm = w >> 1, wn = w & 1, lr = lane & 15, lg = lane >> 4;
    #pragma unroll
    for (int mi = 0; mi < 4; ++mi)
        #pragma unroll
        for (int ni = 0; ni < 4; ++ni)
            #pragma unroll
            for (int j = 0; j < 4; ++j) {
                int gm = tm * 128 + wm * 64 + mi * 16 + lg * 4 + j;
                int gn = tn * 128 + wn * 64 + ni * 16 + lr;
                float v = acc[mi][ni][j] + bias[gn] * bscale;
                int b = gm >> 11, s = gm & (Sdim - 1);
                int h = gn >> 6, d = gn & (Ddim - 1);
                size_t bh = (size_t)(b * Hdim + h);
                if (z == 0) {
                    Qb[(bh * Sdim + s) * Ddim + d] = f2b(v);
                } else if (z == 1) {
                    size_t idx = ((bh * (Sdim / 16) + (s >> 4)) * 8 + (d >> 3)) * 128
                               + (s & 15) * 8 + (d & 7);
                    Kswz[idx] = f2b(v);
                } else {
                    size_t idx = (((bh * (Sdim / 32) + (s >> 5)) * 4 + (d >> 4)) * 4
                               + ((s >> 3) & 3)) * 128 + (d & 15) * 8 + (s & 7);
                    Vswz[idx] = f2b(v);
                }
            }
}

// ---- Kernel 2: fused attention v12 (r17 champion) + exp2 softmax.
// Scores are pre-scaled by log2e at projection, so softmax uses exp2f
// (bare v_exp_f32, no per-element multiply). Otherwise identical to r17.
__global__ __launch_bounds__(256) void k_attn(
    const bf16_t* __restrict__ Qb, const bf16_t* __restrict__ Kswz,
    const bf16_t* __restrict__ Vswz, float* __restrict__ P, bf16_t* __restrict__ AOb) {
    const int wg = blockIdx.x;
    const int id = ((wg & 7) << 7) | (wg >> 3);   // bijective XCD swizzle
    const int bh = id >> 5, qt = id & 31;
    const int b = bh >> 4, h = bh & 15;
    const int tid = threadIdx.x, lane = tid & 63, w = tid >> 6;
    const int lr = lane & 15, lg = lane >> 4;

    __shared__ bf16_t Ps[2][4][16][132];   // double-buffered per-wave P bands
    __shared__ float sum_lds[4][64];       // phase-1 partial row sums

    const bf16_t* Qp0 = Qb + ((size_t)bh * Sdim + qt * 64) * Ddim;       // block base
    const bf16_t* Qp  = Qp0 + (size_t)(w * 16) * Ddim;                   // wave's rows
    const bf16_t* Kp = Kswz + (size_t)bh * Sdim * Ddim;   // fragment-major
    const bf16_t* Vp = Vswz + (size_t)bh * Ddim * Sdim;   // fragment-major
    float* Pp = P + (size_t)bh * Sdim * Sdim + (size_t)(qt * 64 + w * 16) * Sdim;

    // ---------------- Phase 1: column-split row sums of exp2(s) ------------
    {
        bf16x8 qf1[4][2];
        #pragma unroll
        for (int rg = 0; rg < 4; ++rg)
            #pragma unroll
            for (int kk = 0; kk < 2; ++kk)
                qf1[rg][kk] = *(const bf16x8*)(Qp0 + (rg * 16 + lr) * Ddim + kk * 32 + lg * 8);

        float lsum[4][4];
        #pragma unroll
        for (int rg = 0; rg < 4; ++rg)
            #pragma unroll
            for (int j = 0; j < 4; ++j) lsum[rg][j] = 0.f;

        const bf16_t* Kw = Kp + (size_t)w * 32 * 1024;   // wave's 32 fragments
        bf16x8 bA[2][2], bB[2][2], bC[2][2];
#define LOADG(buf, g) { \
            _Pragma("unroll") \
            for (int t = 0; t < 2; ++t) { \
                const bf16_t* kp = Kw + (size_t)((g) * 2 + t) * 1024 + lane * 8; \
                buf[t][0] = *(const bf16x8*)(kp); \
                buf[t][1] = *(const bf16x8*)(kp + 512); \
            } }
#define COMPG(buf) { \
            f32x4 sv[2][4]; \
            __builtin_amdgcn_s_setprio(1); \
            _Pragma("unroll") \
            for (int t = 0; t < 2; ++t) \
                _Pragma("unroll") \
                for (int rg = 0; rg < 4; ++rg) { \
                    f32x4 s = (f32x4){0.f, 0.f, 0.f, 0.f}; \
                    s = __builtin_amdgcn_mfma_f32_16x16x32_bf16(qf1[rg][0], buf[t][0], s, 0, 0, 0); \
                    s = __builtin_amdgcn_mfma_f32_16x16x32_bf16(qf1[rg][1], buf[t][1], s, 0, 0, 0); \
                    sv[t][rg] = s; \
                } \
            __builtin_amdgcn_s_setprio(0); \
            _Pragma("unroll") \
            for (int t = 0; t < 2; ++t) \
                _Pragma("unroll") \
                for (int rg = 0; rg < 4; ++rg) \
                    _Pragma("unroll") \
                    for (int j = 0; j < 4; ++j) \
                        lsum[rg][j] += exp2f(sv[t][rg][j]); }
        LOADG(bA, 0); LOADG(bB, 1);
        for (int g = 0; g < 12; g += 3) {
            LOADG(bC, g + 2); COMPG(bA);
            LOADG(bA, g + 3); COMPG(bB);
            LOADG(bB, g + 4); COMPG(bC);
        }
        LOADG(bC, 14); COMPG(bA);
        LOADG(bA, 15); COMPG(bB);
        COMPG(bC); COMPG(bA);
#undef LOADG
#undef COMPG
        #pragma unroll
        for (int mask = 1; mask <= 8; mask <<= 1)
            #pragma unroll
            for (int rg = 0; rg < 4; ++rg)
                #pragma unroll
                for (int j = 0; j < 4; ++j)
                    lsum[rg][j] += __shfl_xor(lsum[rg][j], mask);
        if (lr == 0)
            #pragma unroll
            for (int rg = 0; rg < 4; ++rg)
                #pragma unroll
                for (int j = 0; j < 4; ++j)
                    sum_lds[w][rg * 16 + lg * 4 + j] = lsum[rg][j];
    }
    __syncthreads();
    float il[4];
    #pragma unroll
    for (int j = 0; j < 4; ++j) {
        int row = w * 16 + lg * 4 + j;
        il[j] = 1.0f / (sum_lds[0][row] + sum_lds[1][row] +
                        sum_lds[2][row] + sum_lds[3][row]);
    }

    // Q fragments for phase 2 (wave's own 16 rows).
    bf16x8 qf[2];
    #pragma unroll
    for (int kk = 0; kk < 2; ++kk)
        qf[kk] = *(const bf16x8*)(Qp + lr * Ddim + kk * 32 + lg * 8);

    // ---------------- Phase 2: pipelined P store + O = P.V ----------------
    f32x4 oacc[4];
    #pragma unroll
    for (int nd = 0; nd < 4; ++nd) oacc[nd] = (f32x4){0.f, 0.f, 0.f, 0.f};

    for (int kt = 0; kt < Sdim / KVB; ++kt) {
        const int cur = kt & 1, prev = cur ^ 1;
        bf16x8 kf[8][2];
        #pragma unroll
        for (int ni = 0; ni < 8; ++ni) {
            const bf16_t* kp = Kp + (size_t)(kt * 8 + ni) * 1024 + lane * 8;
            kf[ni][0] = *(const bf16x8*)(kp);
            kf[ni][1] = *(const bf16x8*)(kp + 512);
        }
        bf16x8 vf[4][4];
        #pragma unroll
        for (int ks = 0; ks < 4; ++ks)
            #pragma unroll
            for (int nd = 0; nd < 4; ++nd)
                vf[ks][nd] = *(const bf16x8*)(Vp + ((size_t)(kt * 4 + ks) * 4 + nd) * 512 + lane * 8);
        if (kt > 0) {
            #pragma unroll
            for (int i = 0; i < 8; ++i) {
                int row = 2 * i + (lane >> 5);
                int col0 = (lane & 31) * 4;
                bf16x4 p4 = *(const bf16x4*)&Ps[prev][w][row][col0];
                f32x4 o;
                o[0] = (float)p4[0]; o[1] = (float)p4[1];
                o[2] = (float)p4[2]; o[3] = (float)p4[3];
                *(f32x4*)&Pp[(size_t)row * Sdim + (kt - 1) * KVB + col0] = o;
            }
        }
        __builtin_amdgcn_s_setprio(1);
        #pragma unroll
        for (int ni = 0; ni < 8; ++ni) {
            f32x4 s = (f32x4){0.f, 0.f, 0.f, 0.f};
            s = __builtin_amdgcn_mfma_f32_16x16x32_bf16(qf[0], kf[ni][0], s, 0, 0, 0);
            s = __builtin_amdgcn_mfma_f32_16x16x32_bf16(qf[1], kf[ni][1], s, 0, 0, 0);
            #pragma unroll
            for (int j = 0; j < 4; ++j)
                Ps[cur][w][lg * 4 + j][ni * 16 + lr] = f2b(exp2f(s[j]) * il[j]);
        }
        __builtin_amdgcn_s_setprio(0);
        __builtin_amdgcn_s_setprio(1);
        #pragma unroll
        for (int ks = 0; ks < 4; ++ks) {
            bf16x8 pa = *(const bf16x8*)&Ps[cur][w][lr][ks * 32 + lg * 8];
            #pragma unroll
            for (int nd = 0; nd < 4; ++nd)
                oacc[nd] = __builtin_amdgcn_mfma_f32_16x16x32_bf16(pa, vf[ks][nd], oacc[nd], 0, 0, 0);
        }
        __builtin_amdgcn_s_setprio(0);
    }
    // epilogue: store last tile's band (band index 15&1 = 1)
    #pragma unroll
    for (int i = 0; i < 8; ++i) {
        int row = 2 * i + (lane >> 5);
        int col0 = (lane & 31) * 4;
        bf16x4 p4 = *(const bf16x4*)&Ps[1][w][row][col0];
        f32x4 o;
        o[0] = (float)p4[0]; o[1] = (float)p4[1];
        o[2] = (float)p4[2]; o[3] = (float)p4[3];
        *(f32x4*)&Pp[(size_t)row * Sdim + (Sdim - KVB) + col0] = o;
    }

    // epilogue: AO bf16 [B,S,E]
    #pragma unroll
    for (int nd = 0; nd < 4; ++nd)
        #pragma unroll
        for (int j = 0; j < 4; ++j) {
            int s = qt * 64 + w * 16 + lg * 4 + j;
            int d = nd * 16 + lr;
            AOb[((size_t)(b * Sdim + s)) * Edim + h * Ddim + d] = f2b(oacc[nd][j]);
        }
}

// ---- Kernel 3: output = AO @ Wo^T + bo -> d_out f32, m97-class GEMM.
__global__ __launch_bounds__(256) void k_oproj(
    const bf16_t* __restrict__ AOb, const bf16_t* __restrict__ Wob,
    const float* __restrict__ bo, float* __restrict__ out) {
    f32x4 acc[4][4];
    gemm_async(AOb + (size_t)blockIdx.y * 128 * Edim,
               Wob + (size_t)blockIdx.x * 128 * Edim, Edim, acc);
    const int tid = threadIdx.x, lane = tid & 63, w = tid >> 6;
    const int wm = w >> 1, wn = w & 1, lr = lane & 15, lg = lane >> 4;
    #pragma unroll
    for (int mi = 0; mi < 4; ++mi)
        #pragma unroll
        for (int ni = 0; ni < 4; ++ni)
            #pragma unroll
            for (int j = 0; j < 4; ++j) {
                int gm = blockIdx.y * 128 + wm * 64 + mi * 16 + lg * 4 + j;
                int gn = blockIdx.x * 128 + wn * 64 + ni * 16 + lr;
                out[(size_t)gm * Edim + gn] = acc[mi][ni][j] + bo[gn];
            }
}

extern "C" void kernel_launch(void* const* d_in, const int* in_sizes, int n_in,
                              void* d_out, int out_size, void* d_ws, size_t ws_size,
                              hipStream_t stream) {
    const float* query = (const float*)d_in[0];
    const float* key_  = (const float*)d_in[1];
    const float* value = (const float*)d_in[2];
    const float* Wq = (const float*)d_in[3];
    const float* bq = (const float*)d_in[4];
    const float* Wk = (const float*)d_in[5];
    const float* bk = (const float*)d_in[6];
    const float* Wv = (const float*)d_in[7];
    const float* bv = (const float*)d_in[8];
    const float* Wo = (const float*)d_in[9];
    const float* bo = (const float*)d_in[10];

    float* out = (float*)d_out;                      // [4096][1024]
    float* P = out + (size_t)MROWS * Edim;           // [32][2048][2048] attn weights
    const size_t PSZ = (size_t)32 * Sdim * Sdim;     // 134217728 floats

    const size_t WSZ = (size_t)Edim * Edim;                 // 1M elems per W
    const size_t HSD = (size_t)Bdim * Hdim * Sdim * Ddim;   // 4M elems
    bf16_t* Wb   = (bf16_t*)d_ws;       // 4 x [E,E]  (Wq*QSCALE, Wk, Wv, Wo)
    bf16_t* Qb   = Wb + 4 * WSZ;        // [B,H,S,D]  (pre-scaled)
    bf16_t* Kswz = Qb + HSD;            // fragment-major K
    bf16_t* Vswz = Kswz + HSD;          // fragment-major V
    bf16_t* AOb  = Vswz + HSD;          // [B,S,E]
    // Xb scratch lives in the TAIL of the P region (24MB of its last 48MB);
    // k_proj consumes it before k_attn overwrites all of P.
    bf16_t* Xb   = (bf16_t*)(P + PSZ - 6 * 1024 * 1024);

    k_convert<<<dim3(2048, 7), 256, 0, stream>>>(Wq, Wk, Wv, Wo, query, key_, value,
                                                 Wb, Xb);
    k_proj<<<dim3(8, 32, 3), 256, 0, stream>>>(Xb, Wb, bq, bk, bv, Qb, Kswz, Vswz);
    k_attn<<<dim3(1024), 256, 0, stream>>>(Qb, Kswz, Vswz, P, AOb);
    k_oproj<<<dim3(8, 32, 1), 256, 0, stream>>>(AOb, Wb + 3 * WSZ, bo, out);
}

// Round 21
// 266.821 us; speedup vs baseline: 1.0645x; 1.0645x over previous
//
#include <hip/hip_runtime.h>
#include <hip/hip_bf16.h>
#include <cstdint>
#include <cstddef>

#define Bdim 2
#define Sdim 2048
#define Edim 1024
#define Hdim 16
#define Ddim 64
#define KVB 128
#define MROWS (Bdim*Sdim)

typedef __bf16 bf16_t;
typedef __attribute__((ext_vector_type(8))) __bf16 bf16x8;
typedef __attribute__((ext_vector_type(4))) __bf16 bf16x4;
typedef __attribute__((ext_vector_type(4))) float f32x4;

typedef __attribute__((address_space(3))) uint8_t lds8_t;
typedef const __attribute__((address_space(1))) uint8_t glb8_t;

__device__ inline bf16_t f2b(float x) {
    unsigned u = __builtin_bit_cast(unsigned, x);
    unsigned r = u + 0x7fffu + ((u >> 16) & 1u);
    return __builtin_bit_cast(bf16_t, (unsigned short)(r >> 16));
}

// m97-class bf16 GEMM core: C[128x128] = A[128xK] * B^T (B row-major [128-col
// band][K]). 4 waves 2x2, 16x16x32 MFMA, 4x4 frags/wave. Staging via
// global_load_lds width=16 into LINEAR LDS [128][32] bf16.
__device__ inline void gemm_async(const bf16_t* A, const bf16_t* B, int K,
                                  f32x4 (&acc)[4][4]) {
    __shared__ __align__(16) bf16_t As[128 * 32];
    __shared__ __align__(16) bf16_t Bs[128 * 32];
    const int tid = threadIdx.x;
    const int lane = tid & 63;
    const int w = tid >> 6;
    const int wm = w >> 1, wn = w & 1;
    const int lr = lane & 15, lg = lane >> 4;

    #pragma unroll
    for (int mi = 0; mi < 4; ++mi)
        #pragma unroll
        for (int ni = 0; ni < 4; ++ni)
            acc[mi][ni] = (f32x4){0.f, 0.f, 0.f, 0.f};

    const int srow = (lane >> 2);
    const int scol = (lane & 3) * 8;

    for (int kt = 0; kt < K; kt += 32) {
        __syncthreads();
        #pragma unroll
        for (int i = 0; i < 2; ++i) {
            const int chunk = w * 2 + i;
            const int row = chunk * 16 + srow;
            __builtin_amdgcn_global_load_lds(
                (glb8_t*)(A + (size_t)row * K + kt + scol),
                (lds8_t*)(As + chunk * 512), 16, 0, 0);
            __builtin_amdgcn_global_load_lds(
                (glb8_t*)(B + (size_t)row * K + kt + scol),
                (lds8_t*)(Bs + chunk * 512), 16, 0, 0);
        }
        __syncthreads();
        bf16x8 af[4], bf[4];
        #pragma unroll
        for (int mi = 0; mi < 4; ++mi)
            af[mi] = *(const bf16x8*)&As[(wm * 64 + mi * 16 + lr) * 32 + lg * 8];
        #pragma unroll
        for (int ni = 0; ni < 4; ++ni)
            bf[ni] = *(const bf16x8*)&Bs[(wn * 64 + ni * 16 + lr) * 32 + lg * 8];
        #pragma unroll
        for (int mi = 0; mi < 4; ++mi)
            #pragma unroll
            for (int ni = 0; ni < 4; ++ni)
                acc[mi][ni] = __builtin_amdgcn_mfma_f32_16x16x32_bf16(
                    af[mi], bf[ni], acc[mi][ni], 0, 0, 0);
    }
}

// ---- Kernel 0: convert weights AND the 3 input activations to bf16.
__global__ __launch_bounds__(256) void k_convert(
    const float* __restrict__ Wq, const float* __restrict__ Wk,
    const float* __restrict__ Wv, const float* __restrict__ Wo,
    const float* __restrict__ xq, const float* __restrict__ xk,
    const float* __restrict__ xv,
    bf16_t* __restrict__ Wb, bf16_t* __restrict__ Xb) {
    const int z = blockIdx.y;
    const float* src;
    bf16_t* d;
    float scale = 1.0f;
    if (z < 4) {
        if (blockIdx.x >= 512) return;
        src = (z == 0) ? Wq : (z == 1) ? Wk : (z == 2) ? Wv : Wo;
        scale = (z == 0) ? 0.125f : 1.0f;
        d = Wb + (size_t)z * Edim * Edim;
    } else {
        src = (z == 4) ? xq : (z == 5) ? xk : xv;
        d = Xb + (size_t)(z - 4) * MROWS * Edim;
    }
    const size_t i = (size_t)blockIdx.x * 256 + threadIdx.x;
    const float4* s4 = (const float4*)(src + i * 8);
    float4 a = s4[0], b = s4[1];
    bf16x8 v;
    v[0] = f2b(a.x * scale); v[1] = f2b(a.y * scale);
    v[2] = f2b(a.z * scale); v[3] = f2b(a.w * scale);
    v[4] = f2b(b.x * scale); v[5] = f2b(b.y * scale);
    v[6] = f2b(b.z * scale); v[7] = f2b(b.w * scale);
    *(bf16x8*)(d + i * 8) = v;
}

// ---- Kernel 1: QKV projections, m97-class bf16 GEMM.
// Q (pre-scaled by 0.125) -> [B,H,S,D]; K,V -> MFMA-fragment-major swizzled:
//   Kswz[bh][s/16][d/8][s%16][d%8]
//   Vswz[bh][s/32][d/16][(s/8)%4][d%16][s%8]
__global__ __launch_bounds__(256) void k_proj(
    const bf16_t* __restrict__ Xb, const bf16_t* __restrict__ Wb,
    const float* __restrict__ bq, const float* __restrict__ bk, const float* __restrict__ bv,
    bf16_t* __restrict__ Qb, bf16_t* __restrict__ Kswz, bf16_t* __restrict__ Vswz) {
    const int z = blockIdx.z;
    const bf16_t* X = Xb + (size_t)z * MROWS * Edim;
    const bf16_t* W = Wb + (size_t)z * Edim * Edim;
    const float* bias = (z == 0) ? bq : (z == 1) ? bk : bv;
    const float bscale = (z == 0) ? 0.125f : 1.0f;
    const int tm = blockIdx.y, tn = blockIdx.x;
    f32x4 acc[4][4];
    gemm_async(X + (size_t)tm * 128 * Edim, W + (size_t)tn * 128 * Edim, Edim, acc);
    const int tid = threadIdx.x, lane = tid & 63, w = tid >> 6;
    const int wm = w >> 1, wn = w & 1, lr = lane & 15, lg = lane >> 4;
    #pragma unroll
    for (int mi = 0; mi < 4; ++mi)
        #pragma unroll
        for (int ni = 0; ni < 4; ++ni)
            #pragma unroll
            for (int j = 0; j < 4; ++j) {
                int gm = tm * 128 + wm * 64 + mi * 16 + lg * 4 + j;
                int gn = tn * 128 + wn * 64 + ni * 16 + lr;
                float v = acc[mi][ni][j] + bias[gn] * bscale;
                int b = gm >> 11, s = gm & (Sdim - 1);
                int h = gn >> 6, d = gn & (Ddim - 1);
                size_t bh = (size_t)(b * Hdim + h);
                if (z == 0) {
                    Qb[(bh * Sdim + s) * Ddim + d] = f2b(v);
                } else if (z == 1) {
                    size_t idx = ((bh * (Sdim / 16) + (s >> 4)) * 8 + (d >> 3)) * 128
                               + (s & 15) * 8 + (d & 7);
                    Kswz[idx] = f2b(v);
                } else {
                    size_t idx = (((bh * (Sdim / 32) + (s >> 5)) * 4 + (d >> 4)) * 4
                               + ((s >> 3) & 3)) * 128 + (d & 15) * 8 + (s & 7);
                    Vswz[idx] = f2b(v);
                }
            }
}

// ---- Kernel 2: fused attention v12 (r17 champion, restored verbatim).
// Phase 1: column-split row sums (wave w covers cols [w*512,(w+1)*512) for
// all 64 block rows; 3-buffer load rotation, setprio around MFMA).
// Phase 2: row-split; fragment-contiguous K/V loads issued before prev-tile
// P stores; double-buffered LDS P bands; coalesced f32x4 P stores.
__global__ __launch_bounds__(256) void k_attn(
    const bf16_t* __restrict__ Qb, const bf16_t* __restrict__ Kswz,
    const bf16_t* __restrict__ Vswz, float* __restrict__ P, bf16_t* __restrict__ AOb) {
    const int wg = blockIdx.x;
    const int id = ((wg & 7) << 7) | (wg >> 3);   // bijective XCD swizzle
    const int bh = id >> 5, qt = id & 31;
    const int b = bh >> 4, h = bh & 15;
    const int tid = threadIdx.x, lane = tid & 63, w = tid >> 6;
    const int lr = lane & 15, lg = lane >> 4;

    __shared__ bf16_t Ps[2][4][16][132];   // double-buffered per-wave P bands
    __shared__ float sum_lds[4][64];       // phase-1 partial row sums

    const bf16_t* Qp0 = Qb + ((size_t)bh * Sdim + qt * 64) * Ddim;       // block base
    const bf16_t* Qp  = Qp0 + (size_t)(w * 16) * Ddim;                   // wave's rows
    const bf16_t* Kp = Kswz + (size_t)bh * Sdim * Ddim;   // fragment-major
    const bf16_t* Vp = Vswz + (size_t)bh * Ddim * Sdim;   // fragment-major
    float* Pp = P + (size_t)bh * Sdim * Sdim + (size_t)(qt * 64 + w * 16) * Sdim;

    // ---------------- Phase 1: column-split row sums of exp(s) -------------
    {
        bf16x8 qf1[4][2];
        #pragma unroll
        for (int rg = 0; rg < 4; ++rg)
            #pragma unroll
            for (int kk = 0; kk < 2; ++kk)
                qf1[rg][kk] = *(const bf16x8*)(Qp0 + (rg * 16 + lr) * Ddim + kk * 32 + lg * 8);

        float lsum[4][4];
        #pragma unroll
        for (int rg = 0; rg < 4; ++rg)
            #pragma unroll
            for (int j = 0; j < 4; ++j) lsum[rg][j] = 0.f;

        const bf16_t* Kw = Kp + (size_t)w * 32 * 1024;   // wave's 32 fragments
        bf16x8 bA[2][2], bB[2][2], bC[2][2];
#define LOADG(buf, g) { \
            _Pragma("unroll") \
            for (int t = 0; t < 2; ++t) { \
                const bf16_t* kp = Kw + (size_t)((g) * 2 + t) * 1024 + lane * 8; \
                buf[t][0] = *(const bf16x8*)(kp); \
                buf[t][1] = *(const bf16x8*)(kp + 512); \
            } }
#define COMPG(buf) { \
            f32x4 sv[2][4]; \
            __builtin_amdgcn_s_setprio(1); \
            _Pragma("unroll") \
            for (int t = 0; t < 2; ++t) \
                _Pragma("unroll") \
                for (int rg = 0; rg < 4; ++rg) { \
                    f32x4 s = (f32x4){0.f, 0.f, 0.f, 0.f}; \
                    s = __builtin_amdgcn_mfma_f32_16x16x32_bf16(qf1[rg][0], buf[t][0], s, 0, 0, 0); \
                    s = __builtin_amdgcn_mfma_f32_16x16x32_bf16(qf1[rg][1], buf[t][1], s, 0, 0, 0); \
                    sv[t][rg] = s; \
                } \
            __builtin_amdgcn_s_setprio(0); \
            _Pragma("unroll") \
            for (int t = 0; t < 2; ++t) \
                _Pragma("unroll") \
                for (int rg = 0; rg < 4; ++rg) \
                    _Pragma("unroll") \
                    for (int j = 0; j < 4; ++j) \
                        lsum[rg][j] += __expf(sv[t][rg][j]); }
        LOADG(bA, 0); LOADG(bB, 1);
        for (int g = 0; g < 12; g += 3) {
            LOADG(bC, g + 2); COMPG(bA);
            LOADG(bA, g + 3); COMPG(bB);
            LOADG(bB, g + 4); COMPG(bC);
        }
        LOADG(bC, 14); COMPG(bA);
        LOADG(bA, 15); COMPG(bB);
        COMPG(bC); COMPG(bA);
#undef LOADG
#undef COMPG
        #pragma unroll
        for (int mask = 1; mask <= 8; mask <<= 1)
            #pragma unroll
            for (int rg = 0; rg < 4; ++rg)
                #pragma unroll
                for (int j = 0; j < 4; ++j)
                    lsum[rg][j] += __shfl_xor(lsum[rg][j], mask);
        if (lr == 0)
            #pragma unroll
            for (int rg = 0; rg < 4; ++rg)
                #pragma unroll
                for (int j = 0; j < 4; ++j)
                    sum_lds[w][rg * 16 + lg * 4 + j] = lsum[rg][j];
    }
    __syncthreads();
    float il[4];
    #pragma unroll
    for (int j = 0; j < 4; ++j) {
        int row = w * 16 + lg * 4 + j;
        il[j] = 1.0f / (sum_lds[0][row] + sum_lds[1][row] +
                        sum_lds[2][row] + sum_lds[3][row]);
    }

    // Q fragments for phase 2 (wave's own 16 rows).
    bf16x8 qf[2];
    #pragma unroll
    for (int kk = 0; kk < 2; ++kk)
        qf[kk] = *(const bf16x8*)(Qp + lr * Ddim + kk * 32 + lg * 8);

    // ---------------- Phase 2: pipelined P store + O = P.V ----------------
    f32x4 oacc[4];
    #pragma unroll
    for (int nd = 0; nd < 4; ++nd) oacc[nd] = (f32x4){0.f, 0.f, 0.f, 0.f};

    for (int kt = 0; kt < Sdim / KVB; ++kt) {
        const int cur = kt & 1, prev = cur ^ 1;
        bf16x8 kf[8][2];
        #pragma unroll
        for (int ni = 0; ni < 8; ++ni) {
            const bf16_t* kp = Kp + (size_t)(kt * 8 + ni) * 1024 + lane * 8;
            kf[ni][0] = *(const bf16x8*)(kp);
            kf[ni][1] = *(const bf16x8*)(kp + 512);
        }
        bf16x8 vf[4][4];
        #pragma unroll
        for (int ks = 0; ks < 4; ++ks)
            #pragma unroll
            for (int nd = 0; nd < 4; ++nd)
                vf[ks][nd] = *(const bf16x8*)(Vp + ((size_t)(kt * 4 + ks) * 4 + nd) * 512 + lane * 8);
        if (kt > 0) {
            #pragma unroll
            for (int i = 0; i < 8; ++i) {
                int row = 2 * i + (lane >> 5);
                int col0 = (lane & 31) * 4;
                bf16x4 p4 = *(const bf16x4*)&Ps[prev][w][row][col0];
                f32x4 o;
                o[0] = (float)p4[0]; o[1] = (float)p4[1];
                o[2] = (float)p4[2]; o[3] = (float)p4[3];
                *(f32x4*)&Pp[(size_t)row * Sdim + (kt - 1) * KVB + col0] = o;
            }
        }
        __builtin_amdgcn_s_setprio(1);
        #pragma unroll
        for (int ni = 0; ni < 8; ++ni) {
            f32x4 s = (f32x4){0.f, 0.f, 0.f, 0.f};
            s = __builtin_amdgcn_mfma_f32_16x16x32_bf16(qf[0], kf[ni][0], s, 0, 0, 0);
            s = __builtin_amdgcn_mfma_f32_16x16x32_bf16(qf[1], kf[ni][1], s, 0, 0, 0);
            #pragma unroll
            for (int j = 0; j < 4; ++j)
                Ps[cur][w][lg * 4 + j][ni * 16 + lr] = f2b(__expf(s[j]) * il[j]);
        }
        __builtin_amdgcn_s_setprio(0);
        __builtin_amdgcn_s_setprio(1);
        #pragma unroll
        for (int ks = 0; ks < 4; ++ks) {
            bf16x8 pa = *(const bf16x8*)&Ps[cur][w][lr][ks * 32 + lg * 8];
            #pragma unroll
            for (int nd = 0; nd < 4; ++nd)
                oacc[nd] = __builtin_amdgcn_mfma_f32_16x16x32_bf16(pa, vf[ks][nd], oacc[nd], 0, 0, 0);
        }
        __builtin_amdgcn_s_setprio(0);
    }
    // epilogue: store last tile's band (band index 15&1 = 1)
    #pragma unroll
    for (int i = 0; i < 8; ++i) {
        int row = 2 * i + (lane >> 5);
        int col0 = (lane & 31) * 4;
        bf16x4 p4 = *(const bf16x4*)&Ps[1][w][row][col0];
        f32x4 o;
        o[0] = (float)p4[0]; o[1] = (float)p4[1];
        o[2] = (float)p4[2]; o[3] = (float)p4[3];
        *(f32x4*)&Pp[(size_t)row * Sdim + (Sdim - KVB) + col0] = o;
    }

    // epilogue: AO bf16 [B,S,E]
    #pragma unroll
    for (int nd = 0; nd < 4; ++nd)
        #pragma unroll
        for (int j = 0; j < 4; ++j) {
            int s = qt * 64 + w * 16 + lg * 4 + j;
            int d = nd * 16 + lr;
            AOb[((size_t)(b * Sdim + s)) * Edim + h * Ddim + d] = f2b(oacc[nd][j]);
        }
}

// ---- Kernel 3: output = AO @ Wo^T + bo -> d_out f32, m97-class GEMM.
__global__ __launch_bounds__(256) void k_oproj(
    const bf16_t* __restrict__ AOb, const bf16_t* __restrict__ Wob,
    const float* __restrict__ bo, float* __restrict__ out) {
    f32x4 acc[4][4];
    gemm_async(AOb + (size_t)blockIdx.y * 128 * Edim,
               Wob + (size_t)blockIdx.x * 128 * Edim, Edim, acc);
    const int tid = threadIdx.x, lane = tid & 63, w = tid >> 6;
    const int wm = w >> 1, wn = w & 1, lr = lane & 15, lg = lane >> 4;
    #pragma unroll
    for (int mi = 0; mi < 4; ++mi)
        #pragma unroll
        for (int ni = 0; ni < 4; ++ni)
            #pragma unroll
            for (int j = 0; j < 4; ++j) {
                int gm = blockIdx.y * 128 + wm * 64 + mi * 16 + lg * 4 + j;
                int gn = blockIdx.x * 128 + wn * 64 + ni * 16 + lr;
                out[(size_t)gm * Edim + gn] = acc[mi][ni][j] + bo[gn];
            }
}

extern "C" void kernel_launch(void* const* d_in, const int* in_sizes, int n_in,
                              void* d_out, int out_size, void* d_ws, size_t ws_size,
                              hipStream_t stream) {
    const float* query = (const float*)d_in[0];
    const float* key_  = (const float*)d_in[1];
    const float* value = (const float*)d_in[2];
    const float* Wq = (const float*)d_in[3];
    const float* bq = (const float*)d_in[4];
    const float* Wk = (const float*)d_in[5];
    const float* bk = (const float*)d_in[6];
    const float* Wv = (const float*)d_in[7];
    const float* bv = (const float*)d_in[8];
    const float* Wo = (const float*)d_in[9];
    const float* bo = (const float*)d_in[10];

    float* out = (float*)d_out;                      // [4096][1024]
    float* P = out + (size_t)MROWS * Edim;           // [32][2048][2048] attn weights
    const size_t PSZ = (size_t)32 * Sdim * Sdim;     // 134217728 floats

    const size_t WSZ = (size_t)Edim * Edim;                 // 1M elems per W
    const size_t HSD = (size_t)Bdim * Hdim * Sdim * Ddim;   // 4M elems
    bf16_t* Wb   = (bf16_t*)d_ws;       // 4 x [E,E]  (Wq*0.125, Wk, Wv, Wo)
    bf16_t* Qb   = Wb + 4 * WSZ;        // [B,H,S,D]  (pre-scaled)
    bf16_t* Kswz = Qb + HSD;            // fragment-major K
    bf16_t* Vswz = Kswz + HSD;          // fragment-major V
    bf16_t* AOb  = Vswz + HSD;          // [B,S,E]
    // Xb scratch lives in the TAIL of the P region (24MB of its last 48MB);
    // k_proj consumes it before k_attn overwrites all of P.
    bf16_t* Xb   = (bf16_t*)(P + PSZ - 6 * 1024 * 1024);

    k_convert<<<dim3(2048, 7), 256, 0, stream>>>(Wq, Wk, Wv, Wo, query, key_, value,
                                                 Wb, Xb);
    k_proj<<<dim3(8, 32, 3), 256, 0, stream>>>(Xb, Wb, bq, bk, bv, Qb, Kswz, Vswz);
    k_attn<<<dim3(1024), 256, 0, stream>>>(Qb, Kswz, Vswz, P, AOb);
    k_oproj<<<dim3(8, 32, 1), 256, 0, stream>>>(AOb, Wb + 3 * WSZ, bo, out);
}